// Round 6
// baseline (646.765 us; speedup 1.0000x reference)
//
#include <hip/hip_runtime.h>
#include <hip/hip_bf16.h>

// ---------------- types / helpers ----------------
typedef __attribute__((ext_vector_type(8))) short bf16x8;
typedef __attribute__((ext_vector_type(4))) float f32x4;

#define T_TOK 2048
#define HD 1024
#define ID 512
#define NE 16
#define TOPK 4
#define BK 64            // K-panel depth (bf16)
#define WELEM (HD*ID*NE) // elems per weight tensor = 8388608

// pack two fp32 -> two bf16 (truncate): one v_perm_b32
__device__ __forceinline__ unsigned pk2(float a, float b) {
    return __builtin_amdgcn_perm(__float_as_uint(b), __float_as_uint(a),
                                 0x07060302u);
}
// load 8 fp32, convert to bf16x8
__device__ __forceinline__ bf16x8 cvt8(const float* __restrict__ p) {
    float4 a = *(const float4*)p;
    float4 b = *(const float4*)(p + 4);
    union { bf16x8 v; unsigned u[4]; } r;
    r.u[0] = pk2(a.x, a.y); r.u[1] = pk2(a.z, a.w);
    r.u[2] = pk2(b.x, b.y); r.u[3] = pk2(b.z, b.w);
    return r.v;
}
__device__ __forceinline__ short f2bf(float f) {  // RTNE
    unsigned u = __float_as_uint(f);
    return (short)((u + 0x7fffu + ((u >> 16) & 1u)) >> 16);
}

#define MFMA_BF16 __builtin_amdgcn_mfma_f32_16x16x32_bf16

// ---------------- kernel 0: fp32 -> bf16 convert ----------------
__global__ __launch_bounds__(256) void conv_k(const float* __restrict__ src,
                                              short* __restrict__ dst) {
    size_t i = ((size_t)blockIdx.x * 256 + threadIdx.x) * 8;
    union { bf16x8 v; uint4 q; } r;
    r.v = cvt8(src + i);
    *(uint4*)(dst + i) = r.q;
}

// ---------------- kernel 1: router (+ x -> bf16) ----------------
__global__ __launch_bounds__(256) void router_k(
        const float* __restrict__ x, const float* __restrict__ gw,
        const float* __restrict__ eb,
        int* __restrict__ tk_idx, float* __restrict__ tk_w,
        short* __restrict__ xb) {
    int wid  = (blockIdx.x * 256 + threadIdx.x) >> 6;   // token id
    int lane = threadIdx.x & 63;

    const float* xr = x + (size_t)wid * HD + lane * 16;
    float xv[16];
#pragma unroll
    for (int c = 0; c < 4; c++) {
        float4 v = *(const float4*)(xr + c * 4);
        xv[4 * c] = v.x; xv[4 * c + 1] = v.y; xv[4 * c + 2] = v.z; xv[4 * c + 3] = v.w;
    }
    {   // bf16 copy of x, coalesced
        union { uint4 q; unsigned u[4]; } w0, w1;
        w0.u[0] = pk2(xv[0], xv[1]);  w0.u[1] = pk2(xv[2], xv[3]);
        w0.u[2] = pk2(xv[4], xv[5]);  w0.u[3] = pk2(xv[6], xv[7]);
        w1.u[0] = pk2(xv[8], xv[9]);  w1.u[1] = pk2(xv[10], xv[11]);
        w1.u[2] = pk2(xv[12], xv[13]); w1.u[3] = pk2(xv[14], xv[15]);
        short* d = xb + ((size_t)wid << 10) + lane * 16;
        *(uint4*)d = w0.q;
        *(uint4*)(d + 8) = w1.q;
    }

    float logits[NE];
#pragma unroll
    for (int e = 0; e < NE; e++) {
        const float* gr = gw + e * HD + lane * 16;
        float p = 0.f;
#pragma unroll
        for (int c = 0; c < 4; c++) {
            float4 v = *(const float4*)(gr + c * 4);
            p += xv[4 * c] * v.x + xv[4 * c + 1] * v.y +
                 xv[4 * c + 2] * v.z + xv[4 * c + 3] * v.w;
        }
#pragma unroll
        for (int s = 32; s > 0; s >>= 1) p += __shfl_xor(p, s, 64);
        logits[e] = p;
    }

    float scores[NE], sc[NE];
#pragma unroll
    for (int e = 0; e < NE; e++) {
        scores[e] = 1.f / (1.f + __expf(-logits[e]));
        sc[e] = scores[e] + eb[e];
    }

    float gs[4];
#pragma unroll
    for (int g = 0; g < 4; g++) {
        float a = sc[4 * g], b = sc[4 * g + 1], c = sc[4 * g + 2], d = sc[4 * g + 3];
        float h1 = fmaxf(a, b), l1 = fminf(a, b);
        float h2 = fmaxf(c, d), l2 = fminf(c, d);
        gs[g] = fmaxf(h1, h2) + fmaxf(fminf(h1, h2), fmaxf(l1, l2));
    }
    int g0 = 0; float b0 = gs[0];
#pragma unroll
    for (int g = 1; g < 4; g++) if (gs[g] > b0) { b0 = gs[g]; g0 = g; }
    int g1 = -1; float b1 = -1e30f;
#pragma unroll
    for (int g = 0; g < 4; g++) if (g != g0 && gs[g] > b1) { b1 = gs[g]; g1 = g; }

    int taken = 0;
    int bid[TOPK]; float bsc[TOPK]; float wsum = 0.f;
#pragma unroll
    for (int k = 0; k < TOPK; k++) {
        float bv = -1e30f; int bi = 0; float bs = 0.f;
#pragma unroll
        for (int e = 0; e < NE; e++) {
            int grp = e >> 2;
            bool ok = ((grp == g0) || (grp == g1)) && !((taken >> e) & 1);
            if (ok && sc[e] > bv) { bv = sc[e]; bi = e; bs = scores[e]; }
        }
        taken |= (1 << bi);
        bid[k] = bi; bsc[k] = bs; wsum += bs;
    }
    if (lane == 0) {
        float inv = 1.0f / (wsum + 1e-20f);
#pragma unroll
        for (int k = 0; k < TOPK; k++) {
            tk_idx[wid * TOPK + k] = bid[k];
            tk_w[wid * TOPK + k]   = bsc[k] * inv;
        }
    }
}

// ---------------- kernel 2: per-expert token lists ----------------
__global__ __launch_bounds__(256) void assign_k(
        const int* __restrict__ tk_idx, const float* __restrict__ tk_w,
        int* __restrict__ counts, int* __restrict__ tok_list,
        float* __restrict__ w_list) {
    int p = blockIdx.x * 256 + threadIdx.x;   // pair id < T_TOK*TOPK
    int e = tk_idx[p];
    float w = tk_w[p];
    int slot = atomicAdd(&counts[e], 1);
    tok_list[e * T_TOK + slot] = p >> 2;
    w_list[e * T_TOK + slot]  = w;
}

__global__ void offs_k(const int* __restrict__ counts, int* __restrict__ offs) {
    if (threadIdx.x == 0) {
        int a = 0;
#pragma unroll
        for (int e = 0; e < NE; e++) { offs[e] = a; a += counts[e]; }
    }
}

// ---------------- kernel 3: GEMM1 (x @ [gate|up]^T, silu*up -> act) -------
// block tile M=128 x N=64 (gate AND up), BK=64, 4 waves (2x2), wave 64x32.
// VGPR-staged pipeline: prefetch panel kp+1 from global into registers while
// computing panel kp from LDS (overlaps LLC latency with MFMA).
__global__ __launch_bounds__(256) void gemm1_k(
        const short* __restrict__ xb,
        const short* __restrict__ gpb,
        const short* __restrict__ upb,
        const int* __restrict__ counts,
        const int* __restrict__ offs,
        const int* __restrict__ tok_list,
        short* __restrict__ act) {
    __shared__ short xs[128 * BK];
    __shared__ short gs[64 * BK];
    __shared__ short us[64 * BK];
    __shared__ int   tok_s[128];

    int e = blockIdx.z;
    int cnt = counts[e];
    int base = blockIdx.x * 128;
    if (base >= cnt) return;
    int arow0 = offs[e] + base;

    int tid = threadIdx.x;
    if (tid < 128) {
        int s = base + tid;
        tok_s[tid] = (s < cnt) ? tok_list[e * T_TOK + s] : tok_list[e * T_TOK];
    }
    __syncthreads();

    int wv = tid >> 6, lane = tid & 63;
    int qd = lane >> 4, l16 = lane & 15;
    int wm = (wv >> 1) * 64, wn = (wv & 1) * 32;
    int nb0 = blockIdx.y * 64;
    const short* gp = gpb + (size_t)e * ID * HD + (size_t)nb0 * HD;
    const short* up = upb + (size_t)e * ID * HD + (size_t)nb0 * HD;

    // staging sources + swizzled LDS offsets
    const short* xsrc[4]; int xlo[4];
#pragma unroll
    for (int i = 0; i < 4; i++) {
        int idx = i * 256 + tid, r = idx >> 3, c = idx & 7;
        xsrc[i] = xb + ((size_t)tok_s[r] << 10) + (c << 3);
        xlo[i]  = (r << 6) + (((c ^ r) & 7) << 3);
    }
    const short* gsrc[2]; const short* usrc[2]; int blo[2];
#pragma unroll
    for (int i = 0; i < 2; i++) {
        int idx = i * 256 + tid, r = idx >> 3, c = idx & 7;
        gsrc[i] = gp + (size_t)r * HD + (c << 3);
        usrc[i] = up + (size_t)r * HD + (c << 3);
        blo[i]  = (r << 6) + (((c ^ r) & 7) << 3);
    }

    f32x4 accg[4][2] = {};
    f32x4 accu[4][2] = {};

    uint4 px[4], pg[2], pu[2];
#pragma unroll
    for (int i = 0; i < 4; i++) px[i] = *(const uint4*)(xsrc[i]);
#pragma unroll
    for (int i = 0; i < 2; i++) {
        pg[i] = *(const uint4*)(gsrc[i]);
        pu[i] = *(const uint4*)(usrc[i]);
    }

    for (int kp = 0; kp < HD; kp += BK) {
        __syncthreads();   // previous compute done reading LDS
#pragma unroll
        for (int i = 0; i < 4; i++) *(uint4*)&xs[xlo[i]] = px[i];
#pragma unroll
        for (int i = 0; i < 2; i++) {
            *(uint4*)&gs[blo[i]] = pg[i];
            *(uint4*)&us[blo[i]] = pu[i];
        }
        __syncthreads();
        int kn = kp + BK;
        if (kn < HD) {     // prefetch next panel; overlaps compute below
#pragma unroll
            for (int i = 0; i < 4; i++) px[i] = *(const uint4*)(xsrc[i] + kn);
#pragma unroll
            for (int i = 0; i < 2; i++) {
                pg[i] = *(const uint4*)(gsrc[i] + kn);
                pu[i] = *(const uint4*)(usrc[i] + kn);
            }
        }
#pragma unroll
        for (int ks = 0; ks < 2; ks++) {
            int cb = ks * 4 + qd;
            bf16x8 af[4], bg[2], bu[2];
#pragma unroll
            for (int i = 0; i < 4; i++) {
                int r = wm + i * 16 + l16;
                af[i] = *(const bf16x8*)&xs[(r << 6) + (((cb ^ r) & 7) << 3)];
            }
#pragma unroll
            for (int j = 0; j < 2; j++) {
                int r = wn + j * 16 + l16;
                int lo = (r << 6) + (((cb ^ r) & 7) << 3);
                bg[j] = *(const bf16x8*)&gs[lo];
                bu[j] = *(const bf16x8*)&us[lo];
            }
#pragma unroll
            for (int i = 0; i < 4; i++)
#pragma unroll
                for (int j = 0; j < 2; j++) {
                    accg[i][j] = MFMA_BF16(af[i], bg[j], accg[i][j], 0, 0, 0);
                    accu[i][j] = MFMA_BF16(af[i], bu[j], accu[i][j], 0, 0, 0);
                }
        }
    }

    // epilogue: silu(g)*u -> bf16 act rows
#pragma unroll
    for (int i = 0; i < 4; i++)
#pragma unroll
        for (int j = 0; j < 2; j++)
#pragma unroll
            for (int r = 0; r < 4; r++) {
                int m = wm + i * 16 + qd * 4 + r;
                if (base + m < cnt) {
                    float g = accg[i][j][r], u = accu[i][j][r];
                    float a = g / (1.f + __expf(-g)) * u;
                    act[(size_t)(arow0 + m) * ID + nb0 + wn + j * 16 + l16] = f2bf(a);
                }
            }
}

// ---------------- kernel 4: GEMM2 (act @ down^T, scale, scatter-add) ------
// block tile M=128 x N=128 over HD, BK=64, wave 64x64. Same VGPR pipeline;
// round-4 atomicAdd epilogue (known-good).
__global__ __launch_bounds__(256) void gemm2_k(
        const short* __restrict__ act,
        const short* __restrict__ dpb,
        const int* __restrict__ counts,
        const int* __restrict__ offs,
        const int* __restrict__ tok_list,
        const float* __restrict__ w_list,
        float* __restrict__ out) {
    __shared__ short as_[128 * BK];
    __shared__ short ds_[128 * BK];
    __shared__ int   tok_s[128];
    __shared__ float w_s[128];

    int e = blockIdx.z;
    int cnt = counts[e];
    int base = blockIdx.x * 128;
    if (base >= cnt) return;
    int arow0 = offs[e] + base;

    int tid = threadIdx.x;
    if (tid < 128) {
        int s = base + tid;
        if (s < cnt) {
            tok_s[tid] = tok_list[e * T_TOK + s];
            w_s[tid]   = w_list[e * T_TOK + s];
        } else {
            tok_s[tid] = 0;
            w_s[tid]   = 0.f;   // padded rows contribute nothing
        }
    }
    // (tok_s/w_s only read in the epilogue, after many barriers)

    int wv = tid >> 6, lane = tid & 63;
    int qd = lane >> 4, l16 = lane & 15;
    int wm = (wv >> 1) * 64, wn = (wv & 1) * 64;
    int hb0 = blockIdx.y * 128;
    const short* dp = dpb + (size_t)e * HD * ID + (size_t)hb0 * ID;

    const short* asrc[4]; const short* dsrc[4]; int lo[4];
#pragma unroll
    for (int i = 0; i < 4; i++) {
        int idx = i * 256 + tid, r = idx >> 3, c = idx & 7;
        asrc[i] = act + (size_t)(arow0 + r) * ID + (c << 3);
        dsrc[i] = dp + (size_t)r * ID + (c << 3);
        lo[i]   = (r << 6) + (((c ^ r) & 7) << 3);
    }

    f32x4 acc[4][4] = {};
    uint4 pa[4], pd[4];
#pragma unroll
    for (int i = 0; i < 4; i++) {
        pa[i] = *(const uint4*)(asrc[i]);
        pd[i] = *(const uint4*)(dsrc[i]);
    }

    for (int kp = 0; kp < ID; kp += BK) {
        __syncthreads();
#pragma unroll
        for (int i = 0; i < 4; i++) {
            *(uint4*)&as_[lo[i]] = pa[i];
            *(uint4*)&ds_[lo[i]] = pd[i];
        }
        __syncthreads();
        int kn = kp + BK;
        if (kn < ID) {
#pragma unroll
            for (int i = 0; i < 4; i++) {
                pa[i] = *(const uint4*)(asrc[i] + kn);
                pd[i] = *(const uint4*)(dsrc[i] + kn);
            }
        }
#pragma unroll
        for (int ks = 0; ks < 2; ks++) {
            int cb = ks * 4 + qd;
            bf16x8 af[4], bd[4];
#pragma unroll
            for (int i = 0; i < 4; i++) {
                int r = wm + i * 16 + l16;
                af[i] = *(const bf16x8*)&as_[(r << 6) + (((cb ^ r) & 7) << 3)];
                int r2 = wn + i * 16 + l16;
                bd[i] = *(const bf16x8*)&ds_[(r2 << 6) + (((cb ^ r2) & 7) << 3)];
            }
#pragma unroll
            for (int i = 0; i < 4; i++)
#pragma unroll
                for (int j = 0; j < 4; j++)
                    acc[i][j] = MFMA_BF16(af[i], bd[j], acc[i][j], 0, 0, 0);
        }
    }

#pragma unroll
    for (int i = 0; i < 4; i++)
#pragma unroll
        for (int j = 0; j < 4; j++)
#pragma unroll
            for (int r = 0; r < 4; r++) {
                int m = wm + i * 16 + qd * 4 + r;
                float v = acc[i][j][r] * w_s[m];
                atomicAdd(&out[(size_t)tok_s[m] * HD + hb0 + wn + j * 16 + l16], v);
            }
}

// ---------------- launch ----------------
extern "C" void kernel_launch(void* const* d_in, const int* in_sizes, int n_in,
                              void* d_out, int out_size, void* d_ws, size_t ws_size,
                              hipStream_t stream) {
    const float* x  = (const float*)d_in[0];   // hidden_states [T,H]
    const float* gw = (const float*)d_in[1];   // gate_weight  [E,H]
    const float* eb = (const float*)d_in[2];   // e_bias       [E]
    const float* gp = (const float*)d_in[3];   // gate_proj [E,I,H]
    const float* up = (const float*)d_in[4];   // up_proj   [E,I,H]
    const float* dp = (const float*)d_in[5];   // down_proj [E,H,I]

    short* gpb = (short*)d_ws;                  // bf16 weights: 3 x 16.8 MB
    short* upb = gpb + WELEM;
    short* dpb = upb + WELEM;
    short* xb  = dpb + WELEM;                   // x bf16: 2048x1024
    short* act = xb + (size_t)T_TOK * HD;       // (8192+128) x 512 bf16
    int* counts   = (int*)(act + (size_t)(T_TOK * TOPK + 128) * ID);
    int* offs     = counts + NE;
    int* tok_list = offs + NE;                        // E*T
    float* w_list = (float*)(tok_list + NE * T_TOK);  // E*T
    int* tk_idx   = (int*)(w_list + NE * T_TOK);      // T*4
    float* tk_w   = (float*)(tk_idx + T_TOK * TOPK);  // T*4

    hipMemsetAsync(counts, 0, NE * sizeof(int), stream);
    hipMemsetAsync(d_out, 0, (size_t)out_size * sizeof(float), stream);

    conv_k<<<WELEM / 8 / 256, 256, 0, stream>>>(gp, gpb);
    conv_k<<<WELEM / 8 / 256, 256, 0, stream>>>(up, upb);
    conv_k<<<WELEM / 8 / 256, 256, 0, stream>>>(dp, dpb);
    router_k<<<T_TOK / 4, 256, 0, stream>>>(x, gw, eb, tk_idx, tk_w, xb);
    assign_k<<<T_TOK * TOPK / 256, 256, 0, stream>>>(tk_idx, tk_w, counts,
                                                     tok_list, w_list);
    offs_k<<<1, 64, 0, stream>>>(counts, offs);
    gemm1_k<<<dim3(T_TOK / 128, ID / 64, NE), 256, 0, stream>>>(
        xb, gpb, upb, counts, offs, tok_list, act);
    gemm2_k<<<dim3(T_TOK / 128, HD / 128, NE), 256, 0, stream>>>(
        act, dpb, counts, offs, tok_list, w_list, (float*)d_out);
}

// Round 7
// 255.170 us; speedup vs baseline: 2.5346x; 2.5346x over previous
//
#include <hip/hip_runtime.h>
#include <hip/hip_bf16.h>

// ---------------- types / helpers ----------------
typedef __attribute__((ext_vector_type(8))) short bf16x8;
typedef __attribute__((ext_vector_type(4))) float f32x4;

#define T_TOK 2048
#define HD 1024
#define ID 512
#define NE 16
#define TOPK 4
#define BK 64            // K-panel depth (bf16)
#define WELEM (HD*ID*NE) // elems per weight tensor = 8388608

// pack two fp32 -> two bf16 (truncate): one v_perm_b32
__device__ __forceinline__ unsigned pk2(float a, float b) {
    return __builtin_amdgcn_perm(__float_as_uint(b), __float_as_uint(a),
                                 0x07060302u);
}
// load 8 fp32, convert to bf16x8
__device__ __forceinline__ bf16x8 cvt8(const float* __restrict__ p) {
    float4 a = *(const float4*)p;
    float4 b = *(const float4*)(p + 4);
    union { bf16x8 v; unsigned u[4]; } r;
    r.u[0] = pk2(a.x, a.y); r.u[1] = pk2(a.z, a.w);
    r.u[2] = pk2(b.x, b.y); r.u[3] = pk2(b.z, b.w);
    return r.v;
}
__device__ __forceinline__ short f2bf(float f) {  // RTNE
    unsigned u = __float_as_uint(f);
    return (short)((u + 0x7fffu + ((u >> 16) & 1u)) >> 16);
}

#define MFMA_BF16 __builtin_amdgcn_mfma_f32_16x16x32_bf16

// ---------------- kernel 0: fp32 -> bf16 convert ----------------
__global__ __launch_bounds__(256) void conv_k(const float* __restrict__ src,
                                              short* __restrict__ dst) {
    size_t i = ((size_t)blockIdx.x * 256 + threadIdx.x) * 8;
    union { bf16x8 v; uint4 q; } r;
    r.v = cvt8(src + i);
    *(uint4*)(dst + i) = r.q;
}

// ---------------- kernel 1: router (+ x -> bf16) ----------------
__global__ __launch_bounds__(256) void router_k(
        const float* __restrict__ x, const float* __restrict__ gw,
        const float* __restrict__ eb,
        int* __restrict__ tk_idx, float* __restrict__ tk_w,
        short* __restrict__ xb) {
    int wid  = (blockIdx.x * 256 + threadIdx.x) >> 6;   // token id
    int lane = threadIdx.x & 63;

    const float* xr = x + (size_t)wid * HD + lane * 16;
    float xv[16];
#pragma unroll
    for (int c = 0; c < 4; c++) {
        float4 v = *(const float4*)(xr + c * 4);
        xv[4 * c] = v.x; xv[4 * c + 1] = v.y; xv[4 * c + 2] = v.z; xv[4 * c + 3] = v.w;
    }
    {   // bf16 copy of x, coalesced
        union { uint4 q; unsigned u[4]; } w0, w1;
        w0.u[0] = pk2(xv[0], xv[1]);  w0.u[1] = pk2(xv[2], xv[3]);
        w0.u[2] = pk2(xv[4], xv[5]);  w0.u[3] = pk2(xv[6], xv[7]);
        w1.u[0] = pk2(xv[8], xv[9]);  w1.u[1] = pk2(xv[10], xv[11]);
        w1.u[2] = pk2(xv[12], xv[13]); w1.u[3] = pk2(xv[14], xv[15]);
        short* d = xb + ((size_t)wid << 10) + lane * 16;
        *(uint4*)d = w0.q;
        *(uint4*)(d + 8) = w1.q;
    }

    float logits[NE];
#pragma unroll
    for (int e = 0; e < NE; e++) {
        const float* gr = gw + e * HD + lane * 16;
        float p = 0.f;
#pragma unroll
        for (int c = 0; c < 4; c++) {
            float4 v = *(const float4*)(gr + c * 4);
            p += xv[4 * c] * v.x + xv[4 * c + 1] * v.y +
                 xv[4 * c + 2] * v.z + xv[4 * c + 3] * v.w;
        }
#pragma unroll
        for (int s = 32; s > 0; s >>= 1) p += __shfl_xor(p, s, 64);
        logits[e] = p;
    }

    float scores[NE], sc[NE];
#pragma unroll
    for (int e = 0; e < NE; e++) {
        scores[e] = 1.f / (1.f + __expf(-logits[e]));
        sc[e] = scores[e] + eb[e];
    }

    float gs[4];
#pragma unroll
    for (int g = 0; g < 4; g++) {
        float a = sc[4 * g], b = sc[4 * g + 1], c = sc[4 * g + 2], d = sc[4 * g + 3];
        float h1 = fmaxf(a, b), l1 = fminf(a, b);
        float h2 = fmaxf(c, d), l2 = fminf(c, d);
        gs[g] = fmaxf(h1, h2) + fmaxf(fminf(h1, h2), fmaxf(l1, l2));
    }
    int g0 = 0; float b0 = gs[0];
#pragma unroll
    for (int g = 1; g < 4; g++) if (gs[g] > b0) { b0 = gs[g]; g0 = g; }
    int g1 = -1; float b1 = -1e30f;
#pragma unroll
    for (int g = 0; g < 4; g++) if (g != g0 && gs[g] > b1) { b1 = gs[g]; g1 = g; }

    int taken = 0;
    int bid[TOPK]; float bsc[TOPK]; float wsum = 0.f;
#pragma unroll
    for (int k = 0; k < TOPK; k++) {
        float bv = -1e30f; int bi = 0; float bs = 0.f;
#pragma unroll
        for (int e = 0; e < NE; e++) {
            int grp = e >> 2;
            bool ok = ((grp == g0) || (grp == g1)) && !((taken >> e) & 1);
            if (ok && sc[e] > bv) { bv = sc[e]; bi = e; bs = scores[e]; }
        }
        taken |= (1 << bi);
        bid[k] = bi; bsc[k] = bs; wsum += bs;
    }
    if (lane == 0) {
        float inv = 1.0f / (wsum + 1e-20f);
#pragma unroll
        for (int k = 0; k < TOPK; k++) {
            tk_idx[wid * TOPK + k] = bid[k];
            tk_w[wid * TOPK + k]   = bsc[k] * inv;
        }
    }
}

// ---------------- kernel 2: per-expert token lists ----------------
__global__ __launch_bounds__(256) void assign_k(
        const int* __restrict__ tk_idx,
        int* __restrict__ counts, int* __restrict__ tok_list,
        int* __restrict__ pair_slot) {
    int p = blockIdx.x * 256 + threadIdx.x;   // pair id < T_TOK*TOPK
    int e = tk_idx[p];
    int slot = atomicAdd(&counts[e], 1);
    tok_list[e * T_TOK + slot] = p >> 2;
    pair_slot[p] = slot;
}

__global__ void offs_k(const int* __restrict__ counts, int* __restrict__ offs) {
    if (threadIdx.x == 0) {
        int a = 0;
#pragma unroll
        for (int e = 0; e < NE; e++) { offs[e] = a; a += counts[e]; }
    }
}

// ---------------- kernel 3: GEMM1 (x @ [gate|up]^T, silu*up -> act) -------
// grid (n_slices=8, m_tiles=16, experts=16): n-slices fastest so blocks
// sharing an x-tile run temporally adjacent (L2/L3 locality).
// block tile M=128 x N=64 (gate AND up), BK=64, 4 waves (2x2), wave 64x32.
// r4-style inline staging (stage -> sync -> compute).
__global__ __launch_bounds__(256) void gemm1_k(
        const short* __restrict__ xb,
        const short* __restrict__ gpb,
        const short* __restrict__ upb,
        const int* __restrict__ counts,
        const int* __restrict__ offs,
        const int* __restrict__ tok_list,
        short* __restrict__ act) {
    __shared__ short xs[128 * BK];
    __shared__ short gs[64 * BK];
    __shared__ short us[64 * BK];
    __shared__ int   tok_s[128];

    int e = blockIdx.z;
    int cnt = counts[e];
    int base = blockIdx.y * 128;
    if (base >= cnt) return;
    int arow0 = offs[e] + base;

    int tid = threadIdx.x;
    if (tid < 128) {
        int s = base + tid;
        tok_s[tid] = (s < cnt) ? tok_list[e * T_TOK + s] : tok_list[e * T_TOK];
    }

    int wv = tid >> 6, lane = tid & 63;
    int qd = lane >> 4, l16 = lane & 15;
    int wm = (wv >> 1) * 64, wn = (wv & 1) * 32;
    int nb0 = blockIdx.x * 64;
    const short* gp = gpb + (size_t)e * ID * HD + (size_t)nb0 * HD;
    const short* up = upb + (size_t)e * ID * HD + (size_t)nb0 * HD;

    f32x4 accg[4][2] = {};
    f32x4 accu[4][2] = {};
    __syncthreads();

    for (int kp = 0; kp < HD; kp += BK) {
        // stage x tile: 128 rows x 8 chunks of 16B
#pragma unroll
        for (int i = 0; i < 4; i++) {
            int idx = i * 256 + tid;
            int r = idx >> 3, c = idx & 7;
            *(uint4*)&xs[(r << 6) + (((c ^ r) & 7) << 3)] =
                *(const uint4*)(xb + ((size_t)tok_s[r] << 10) + kp + (c << 3));
        }
        // stage gate/up tiles: 64 rows x 8 chunks
#pragma unroll
        for (int i = 0; i < 2; i++) {
            int idx = i * 256 + tid;
            int r = idx >> 3, c = idx & 7;
            size_t go = (size_t)r * HD + kp + (c << 3);
            int lo = (r << 6) + (((c ^ r) & 7) << 3);
            *(uint4*)&gs[lo] = *(const uint4*)(gp + go);
            *(uint4*)&us[lo] = *(const uint4*)(up + go);
        }
        __syncthreads();
#pragma unroll
        for (int ks = 0; ks < 2; ks++) {
            int cb = ks * 4 + qd;
            bf16x8 af[4], bg[2], bu[2];
#pragma unroll
            for (int i = 0; i < 4; i++) {
                int r = wm + i * 16 + l16;
                af[i] = *(const bf16x8*)&xs[(r << 6) + (((cb ^ r) & 7) << 3)];
            }
#pragma unroll
            for (int j = 0; j < 2; j++) {
                int r = wn + j * 16 + l16;
                int lo = (r << 6) + (((cb ^ r) & 7) << 3);
                bg[j] = *(const bf16x8*)&gs[lo];
                bu[j] = *(const bf16x8*)&us[lo];
            }
#pragma unroll
            for (int i = 0; i < 4; i++)
#pragma unroll
                for (int j = 0; j < 2; j++) {
                    accg[i][j] = MFMA_BF16(af[i], bg[j], accg[i][j], 0, 0, 0);
                    accu[i][j] = MFMA_BF16(af[i], bu[j], accu[i][j], 0, 0, 0);
                }
        }
        __syncthreads();
    }

    // epilogue: silu(g)*u -> bf16 act rows
#pragma unroll
    for (int i = 0; i < 4; i++)
#pragma unroll
        for (int j = 0; j < 2; j++)
#pragma unroll
            for (int r = 0; r < 4; r++) {
                int m = wm + i * 16 + qd * 4 + r;
                if (base + m < cnt) {
                    float g = accg[i][j][r], u = accu[i][j][r];
                    float a = g / (1.f + __expf(-g)) * u;
                    act[(size_t)(arow0 + m) * ID + nb0 + wn + j * 16 + l16] = f2bf(a);
                }
            }
}

// ---------------- kernel 4: GEMM2 (act @ down^T -> yexp fp32) -------------
// grid (h_slices=8, m_tiles=16, experts=16); h-slices fastest (share act).
// block tile M=128 x N=128 over HD, BK=64, wave 64x64. Atomic-free: writes
// per-expert-row yexp; combine_k applies routing weights.
__global__ __launch_bounds__(256) void gemm2_k(
        const short* __restrict__ act,
        const short* __restrict__ dpb,
        const int* __restrict__ counts,
        const int* __restrict__ offs,
        float* __restrict__ yexp) {
    __shared__ short as_[128 * BK];
    __shared__ short ds_[128 * BK];

    int e = blockIdx.z;
    int cnt = counts[e];
    int base = blockIdx.y * 128;
    if (base >= cnt) return;
    int arow0 = offs[e] + base;

    int tid = threadIdx.x;
    int wv = tid >> 6, lane = tid & 63;
    int qd = lane >> 4, l16 = lane & 15;
    int wm = (wv >> 1) * 64, wn = (wv & 1) * 64;
    int hb0 = blockIdx.x * 128;
    const short* dp = dpb + (size_t)e * HD * ID + (size_t)hb0 * ID;

    f32x4 acc[4][4] = {};
    __syncthreads();

    for (int kp = 0; kp < ID; kp += BK) {
#pragma unroll
        for (int i = 0; i < 4; i++) {
            int idx = i * 256 + tid;
            int r = idx >> 3, c = idx & 7;
            int lo = (r << 6) + (((c ^ r) & 7) << 3);
            *(uint4*)&as_[lo] =
                *(const uint4*)(act + (size_t)(arow0 + r) * ID + kp + (c << 3));
            *(uint4*)&ds_[lo] =
                *(const uint4*)(dp + (size_t)r * ID + kp + (c << 3));
        }
        __syncthreads();
#pragma unroll
        for (int ks = 0; ks < 2; ks++) {
            int cb = ks * 4 + qd;
            bf16x8 af[4], bd[4];
#pragma unroll
            for (int i = 0; i < 4; i++) {
                int r = wm + i * 16 + l16;
                af[i] = *(const bf16x8*)&as_[(r << 6) + (((cb ^ r) & 7) << 3)];
                int r2 = wn + i * 16 + l16;
                bd[i] = *(const bf16x8*)&ds_[(r2 << 6) + (((cb ^ r2) & 7) << 3)];
            }
#pragma unroll
            for (int i = 0; i < 4; i++)
#pragma unroll
                for (int j = 0; j < 4; j++)
                    acc[i][j] = MFMA_BF16(af[i], bd[j], acc[i][j], 0, 0, 0);
        }
        __syncthreads();
    }

#pragma unroll
    for (int i = 0; i < 4; i++)
#pragma unroll
        for (int j = 0; j < 4; j++)
#pragma unroll
            for (int r = 0; r < 4; r++) {
                int m = wm + i * 16 + qd * 4 + r;
                if (base + m < cnt)
                    yexp[(size_t)(arow0 + m) * HD + hb0 + wn + j * 16 + l16] =
                        acc[i][j][r];
            }
}

// ---------------- kernel 5: weighted combine (atomic-free) ----------------
// one block per token; thread i covers cols 4i..4i+3.
__global__ __launch_bounds__(256) void combine_k(
        const float* __restrict__ yexp,
        const int* __restrict__ offs,
        const int* __restrict__ tk_idx, const float* __restrict__ tk_w,
        const int* __restrict__ pair_slot,
        float* __restrict__ out) {
    int t = blockIdx.x, i = threadIdx.x;
    float4 acc = {0.f, 0.f, 0.f, 0.f};
#pragma unroll
    for (int k = 0; k < TOPK; k++) {
        int p = t * TOPK + k;
        int e = tk_idx[p];
        int row = offs[e] + pair_slot[p];
        float w = tk_w[p];
        float4 v = *(const float4*)(yexp + (size_t)row * HD + (i << 2));
        acc.x += w * v.x; acc.y += w * v.y;
        acc.z += w * v.z; acc.w += w * v.w;
    }
    *(float4*)(out + (size_t)t * HD + (i << 2)) = acc;
}

// ---------------- launch ----------------
extern "C" void kernel_launch(void* const* d_in, const int* in_sizes, int n_in,
                              void* d_out, int out_size, void* d_ws, size_t ws_size,
                              hipStream_t stream) {
    const float* x  = (const float*)d_in[0];   // hidden_states [T,H]
    const float* gw = (const float*)d_in[1];   // gate_weight  [E,H]
    const float* eb = (const float*)d_in[2];   // e_bias       [E]
    const float* gp = (const float*)d_in[3];   // gate_proj [E,I,H]
    const float* up = (const float*)d_in[4];   // up_proj   [E,I,H]
    const float* dp = (const float*)d_in[5];   // down_proj [E,H,I]

    short* gpb = (short*)d_ws;                  // bf16 weights: 3 x 16.8 MB
    short* upb = gpb + WELEM;
    short* dpb = upb + WELEM;
    short* xb  = dpb + WELEM;                   // x bf16: 2048x1024
    short* act = xb + (size_t)T_TOK * HD;       // (8192+128) x 512 bf16
    int* counts    = (int*)(act + (size_t)(T_TOK * TOPK + 128) * ID);
    int* offs      = counts + NE;
    int* tok_list  = offs + NE;                       // E*T
    int* pair_slot = tok_list + NE * T_TOK;           // T*4
    int* tk_idx    = pair_slot + T_TOK * TOPK;        // T*4
    float* tk_w    = (float*)(tk_idx + T_TOK * TOPK); // T*4
    // yexp fp32 (8192 x 1024 x 4B = 33.55 MB) aliases gpb+upb (dead after
    // gemm1; exact size match). Same-stream ordering makes this safe.
    float* yexp = (float*)gpb;

    hipMemsetAsync(counts, 0, NE * sizeof(int), stream);
    hipMemsetAsync(d_out, 0, (size_t)out_size * sizeof(float), stream);

    conv_k<<<WELEM / 8 / 256, 256, 0, stream>>>(gp, gpb);
    conv_k<<<WELEM / 8 / 256, 256, 0, stream>>>(up, upb);
    conv_k<<<WELEM / 8 / 256, 256, 0, stream>>>(dp, dpb);
    router_k<<<T_TOK / 4, 256, 0, stream>>>(x, gw, eb, tk_idx, tk_w, xb);
    assign_k<<<T_TOK * TOPK / 256, 256, 0, stream>>>(tk_idx, counts,
                                                     tok_list, pair_slot);
    offs_k<<<1, 64, 0, stream>>>(counts, offs);
    gemm1_k<<<dim3(ID / 64, T_TOK / 128, NE), 256, 0, stream>>>(
        xb, gpb, upb, counts, offs, tok_list, act);
    gemm2_k<<<dim3(HD / 128, T_TOK / 128, NE), 256, 0, stream>>>(
        act, dpb, counts, offs, yexp);
    combine_k<<<T_TOK, 256, 0, stream>>>(yexp, offs, tk_idx, tk_w,
                                         pair_slot, (float*)d_out);
}

// Round 8
// 244.951 us; speedup vs baseline: 2.6404x; 1.0417x over previous
//
#include <hip/hip_runtime.h>
#include <hip/hip_bf16.h>

// ---------------- types / helpers ----------------
typedef __attribute__((ext_vector_type(8))) short bf16x8;
typedef __attribute__((ext_vector_type(4))) float f32x4;

#define T_TOK 2048
#define HD 1024
#define ID 512
#define NE 16
#define TOPK 4
#define BK 64            // K-panel depth (bf16)
#define WELEM (HD*ID*NE) // elems per weight tensor = 8388608

// pack two fp32 -> two bf16 (truncate): one v_perm_b32
__device__ __forceinline__ unsigned pk2(float a, float b) {
    return __builtin_amdgcn_perm(__float_as_uint(b), __float_as_uint(a),
                                 0x07060302u);
}
__device__ __forceinline__ bf16x8 cvt8(const float* __restrict__ p) {
    float4 a = *(const float4*)p;
    float4 b = *(const float4*)(p + 4);
    union { bf16x8 v; unsigned u[4]; } r;
    r.u[0] = pk2(a.x, a.y); r.u[1] = pk2(a.z, a.w);
    r.u[2] = pk2(b.x, b.y); r.u[3] = pk2(b.z, b.w);
    return r.v;
}
__device__ __forceinline__ short f2bf(float f) {  // RTNE
    unsigned u = __float_as_uint(f);
    return (short)((u + 0x7fffu + ((u >> 16) & 1u)) >> 16);
}
__device__ __forceinline__ float bf2f(short s) {
    return __uint_as_float(((unsigned)(unsigned short)s) << 16);
}
// async 16B-per-lane global->LDS DMA; lds dest = wave-uniform base + lane*16
__device__ __forceinline__ void load_lds16(const short* g, short* l) {
    __builtin_amdgcn_global_load_lds(
        (const __attribute__((address_space(1))) unsigned*)g,
        (__attribute__((address_space(3))) unsigned*)l, 16, 0, 0);
}

#define MFMA_BF16 __builtin_amdgcn_mfma_f32_16x16x32_bf16

// ---------------- kernel 0: fp32 -> bf16 convert (3 tensors) --------------
__global__ __launch_bounds__(256) void conv_k(
        const float* __restrict__ s0, short* __restrict__ d0,
        const float* __restrict__ s1, short* __restrict__ d1,
        const float* __restrict__ s2, short* __restrict__ d2) {
    const float* src = (blockIdx.y == 0) ? s0 : (blockIdx.y == 1) ? s1 : s2;
    short* dst       = (blockIdx.y == 0) ? d0 : (blockIdx.y == 1) ? d1 : d2;
    size_t i = ((size_t)blockIdx.x * 256 + threadIdx.x) * 8;
    union { bf16x8 v; uint4 q; } r;
    r.v = cvt8(src + i);
    *(uint4*)(dst + i) = r.q;
}

// ---------------- kernel 1: router (+ x -> bf16) ----------------
__global__ __launch_bounds__(256) void router_k(
        const float* __restrict__ x, const float* __restrict__ gw,
        const float* __restrict__ eb,
        int* __restrict__ tk_idx, float* __restrict__ tk_w,
        short* __restrict__ xb) {
    int wid  = (blockIdx.x * 256 + threadIdx.x) >> 6;   // token id
    int lane = threadIdx.x & 63;

    const float* xr = x + (size_t)wid * HD + lane * 16;
    float xv[16];
#pragma unroll
    for (int c = 0; c < 4; c++) {
        float4 v = *(const float4*)(xr + c * 4);
        xv[4 * c] = v.x; xv[4 * c + 1] = v.y; xv[4 * c + 2] = v.z; xv[4 * c + 3] = v.w;
    }
    {   // bf16 copy of x, coalesced
        union { uint4 q; unsigned u[4]; } w0, w1;
        w0.u[0] = pk2(xv[0], xv[1]);  w0.u[1] = pk2(xv[2], xv[3]);
        w0.u[2] = pk2(xv[4], xv[5]);  w0.u[3] = pk2(xv[6], xv[7]);
        w1.u[0] = pk2(xv[8], xv[9]);  w1.u[1] = pk2(xv[10], xv[11]);
        w1.u[2] = pk2(xv[12], xv[13]); w1.u[3] = pk2(xv[14], xv[15]);
        short* d = xb + ((size_t)wid << 10) + lane * 16;
        *(uint4*)d = w0.q;
        *(uint4*)(d + 8) = w1.q;
    }

    float logits[NE];
#pragma unroll
    for (int e = 0; e < NE; e++) {
        const float* gr = gw + e * HD + lane * 16;
        float p = 0.f;
#pragma unroll
        for (int c = 0; c < 4; c++) {
            float4 v = *(const float4*)(gr + c * 4);
            p += xv[4 * c] * v.x + xv[4 * c + 1] * v.y +
                 xv[4 * c + 2] * v.z + xv[4 * c + 3] * v.w;
        }
#pragma unroll
        for (int s = 32; s > 0; s >>= 1) p += __shfl_xor(p, s, 64);
        logits[e] = p;
    }

    float scores[NE], sc[NE];
#pragma unroll
    for (int e = 0; e < NE; e++) {
        scores[e] = 1.f / (1.f + __expf(-logits[e]));
        sc[e] = scores[e] + eb[e];
    }

    float gs[4];
#pragma unroll
    for (int g = 0; g < 4; g++) {
        float a = sc[4 * g], b = sc[4 * g + 1], c = sc[4 * g + 2], d = sc[4 * g + 3];
        float h1 = fmaxf(a, b), l1 = fminf(a, b);
        float h2 = fmaxf(c, d), l2 = fminf(c, d);
        gs[g] = fmaxf(h1, h2) + fmaxf(fminf(h1, h2), fmaxf(l1, l2));
    }
    int g0 = 0; float b0 = gs[0];
#pragma unroll
    for (int g = 1; g < 4; g++) if (gs[g] > b0) { b0 = gs[g]; g0 = g; }
    int g1 = -1; float b1 = -1e30f;
#pragma unroll
    for (int g = 0; g < 4; g++) if (g != g0 && gs[g] > b1) { b1 = gs[g]; g1 = g; }

    int taken = 0;
    int bid[TOPK]; float bsc[TOPK]; float wsum = 0.f;
#pragma unroll
    for (int k = 0; k < TOPK; k++) {
        float bv = -1e30f; int bi = 0; float bs = 0.f;
#pragma unroll
        for (int e = 0; e < NE; e++) {
            int grp = e >> 2;
            bool ok = ((grp == g0) || (grp == g1)) && !((taken >> e) & 1);
            if (ok && sc[e] > bv) { bv = sc[e]; bi = e; bs = scores[e]; }
        }
        taken |= (1 << bi);
        bid[k] = bi; bsc[k] = bs; wsum += bs;
    }
    if (lane == 0) {
        float inv = 1.0f / (wsum + 1e-20f);
#pragma unroll
        for (int k = 0; k < TOPK; k++) {
            tk_idx[wid * TOPK + k] = bid[k];
            tk_w[wid * TOPK + k]   = bsc[k] * inv;
        }
    }
}

// ---------------- kernel 2: per-expert token lists ----------------
__global__ __launch_bounds__(256) void assign_k(
        const int* __restrict__ tk_idx,
        int* __restrict__ counts, int* __restrict__ tok_list,
        int* __restrict__ pair_slot) {
    int p = blockIdx.x * 256 + threadIdx.x;   // pair id < T_TOK*TOPK
    int e = tk_idx[p];
    int slot = atomicAdd(&counts[e], 1);
    tok_list[e * T_TOK + slot] = p >> 2;
    pair_slot[p] = slot;
}

__global__ void offs_k(const int* __restrict__ counts, int* __restrict__ offs) {
    if (threadIdx.x == 0) {
        int a = 0;
#pragma unroll
        for (int e = 0; e < NE; e++) { offs[e] = a; a += counts[e]; }
    }
}

// ---------------- kernel 3: GEMM1 (x @ [gate|up]^T, silu*up -> act) -------
// grid (n_slices=8, m_tiles=16, experts=16). block tile M=128 x N=64
// (gate AND up), BK=64, 4 waves (2x2), wave 64x32.
// Staging via global_load_lds width=16: dest = wave-uniform base + lane*16
// (linear LDS layout); XOR chunk swizzle applied on the SOURCE address, so
// fragment reads keep the conflict-free swizzled indexing.
__global__ __launch_bounds__(256) void gemm1_k(
        const short* __restrict__ xb,
        const short* __restrict__ gpb,
        const short* __restrict__ upb,
        const int* __restrict__ counts,
        const int* __restrict__ offs,
        const int* __restrict__ tok_list,
        short* __restrict__ act) {
    __shared__ short xs[128 * BK];
    __shared__ short gs[64 * BK];
    __shared__ short us[64 * BK];
    __shared__ int   tok_s[128];

    int e = blockIdx.z;
    int cnt = counts[e];
    int base = blockIdx.y * 128;
    if (base >= cnt) return;
    int arow0 = offs[e] + base;

    int tid = threadIdx.x;
    if (tid < 128) {
        int s = base + tid;
        tok_s[tid] = (s < cnt) ? tok_list[e * T_TOK + s] : tok_list[e * T_TOK];
    }
    __syncthreads();

    int wv = tid >> 6, lane = tid & 63;
    int qd = lane >> 4, l16 = lane & 15;
    int wm = (wv >> 1) * 64, wn = (wv & 1) * 32;
    int nb0 = blockIdx.x * 64;
    const short* gp = gpb + (size_t)e * ID * HD + (size_t)nb0 * HD;
    const short* up = upb + (size_t)e * ID * HD + (size_t)nb0 * HD;

    // per-lane swizzled global sources + wave-uniform LDS dest bases
    const short* xsg[4]; short* xld[4];
#pragma unroll
    for (int i = 0; i < 4; i++) {
        int idx = i * 256 + tid, r = idx >> 3, c = idx & 7;
        xsg[i] = xb + ((size_t)tok_s[r] << 10) + (((c ^ r) & 7) << 3);
        xld[i] = &xs[(i * 256 + wv * 64) * 8];
    }
    const short* gsg[2]; const short* usg[2]; short* gld[2]; short* uld[2];
#pragma unroll
    for (int i = 0; i < 2; i++) {
        int idx = i * 256 + tid, r = idx >> 3, c = idx & 7;
        size_t so = (size_t)r * HD + (((c ^ r) & 7) << 3);
        gsg[i] = gp + so;
        usg[i] = up + so;
        gld[i] = &gs[(i * 256 + wv * 64) * 8];
        uld[i] = &us[(i * 256 + wv * 64) * 8];
    }

    f32x4 accg[4][2] = {};
    f32x4 accu[4][2] = {};

    for (int kp = 0; kp < HD; kp += BK) {
        // async DMA: 8 x 1KiB per wave
#pragma unroll
        for (int i = 0; i < 4; i++) load_lds16(xsg[i] + kp, xld[i]);
#pragma unroll
        for (int i = 0; i < 2; i++) {
            load_lds16(gsg[i] + kp, gld[i]);
            load_lds16(usg[i] + kp, uld[i]);
        }
        __syncthreads();   // drains vmcnt, all DMAs landed
#pragma unroll
        for (int ks = 0; ks < 2; ks++) {
            int cb = ks * 4 + qd;
            bf16x8 af[4], bg[2], bu[2];
#pragma unroll
            for (int i = 0; i < 4; i++) {
                int r = wm + i * 16 + l16;
                af[i] = *(const bf16x8*)&xs[(r << 6) + (((cb ^ r) & 7) << 3)];
            }
#pragma unroll
            for (int j = 0; j < 2; j++) {
                int r = wn + j * 16 + l16;
                int lo = (r << 6) + (((cb ^ r) & 7) << 3);
                bg[j] = *(const bf16x8*)&gs[lo];
                bu[j] = *(const bf16x8*)&us[lo];
            }
#pragma unroll
            for (int i = 0; i < 4; i++)
#pragma unroll
                for (int j = 0; j < 2; j++) {
                    accg[i][j] = MFMA_BF16(af[i], bg[j], accg[i][j], 0, 0, 0);
                    accu[i][j] = MFMA_BF16(af[i], bu[j], accu[i][j], 0, 0, 0);
                }
        }
        __syncthreads();   // reads done before next panel's DMA overwrites
    }

    // epilogue: silu(g)*u -> bf16 act rows
#pragma unroll
    for (int i = 0; i < 4; i++)
#pragma unroll
        for (int j = 0; j < 2; j++)
#pragma unroll
            for (int r = 0; r < 4; r++) {
                int m = wm + i * 16 + qd * 4 + r;
                if (base + m < cnt) {
                    float g = accg[i][j][r], u = accu[i][j][r];
                    float a = g / (1.f + __expf(-g)) * u;
                    act[(size_t)(arow0 + m) * ID + nb0 + wn + j * 16 + l16] = f2bf(a);
                }
            }
}

// ---------------- kernel 4: GEMM2 (act @ down^T -> yexp bf16) -------------
// grid (h_slices=8, m_tiles=16, experts=16). block tile M=128 x N=128,
// BK=64, wave 64x64. Same global_load_lds staging. Atomic-free: writes
// per-expert-row yexp (bf16); combine_k applies routing weights.
__global__ __launch_bounds__(256) void gemm2_k(
        const short* __restrict__ act,
        const short* __restrict__ dpb,
        const int* __restrict__ counts,
        const int* __restrict__ offs,
        short* __restrict__ yexp) {
    __shared__ short as_[128 * BK];
    __shared__ short ds_[128 * BK];

    int e = blockIdx.z;
    int cnt = counts[e];
    int base = blockIdx.y * 128;
    if (base >= cnt) return;
    int arow0 = offs[e] + base;

    int tid = threadIdx.x;
    int wv = tid >> 6, lane = tid & 63;
    int qd = lane >> 4, l16 = lane & 15;
    int wm = (wv >> 1) * 64, wn = (wv & 1) * 64;
    int hb0 = blockIdx.x * 128;
    const short* dp = dpb + (size_t)e * HD * ID + (size_t)hb0 * ID;

    const short* asg[4]; const short* dsg[4]; short* ald[4]; short* dld[4];
#pragma unroll
    for (int i = 0; i < 4; i++) {
        int idx = i * 256 + tid, r = idx >> 3, c = idx & 7;
        int sw = ((c ^ r) & 7) << 3;
        asg[i] = act + (size_t)(arow0 + r) * ID + sw;
        dsg[i] = dp + (size_t)r * ID + sw;
        ald[i] = &as_[(i * 256 + wv * 64) * 8];
        dld[i] = &ds_[(i * 256 + wv * 64) * 8];
    }

    f32x4 acc[4][4] = {};

    for (int kp = 0; kp < ID; kp += BK) {
#pragma unroll
        for (int i = 0; i < 4; i++) {
            load_lds16(asg[i] + kp, ald[i]);
            load_lds16(dsg[i] + kp, dld[i]);
        }
        __syncthreads();
#pragma unroll
        for (int ks = 0; ks < 2; ks++) {
            int cb = ks * 4 + qd;
            bf16x8 af[4], bd[4];
#pragma unroll
            for (int i = 0; i < 4; i++) {
                int r = wm + i * 16 + l16;
                af[i] = *(const bf16x8*)&as_[(r << 6) + (((cb ^ r) & 7) << 3)];
                int r2 = wn + i * 16 + l16;
                bd[i] = *(const bf16x8*)&ds_[(r2 << 6) + (((cb ^ r2) & 7) << 3)];
            }
#pragma unroll
            for (int i = 0; i < 4; i++)
#pragma unroll
                for (int j = 0; j < 4; j++)
                    acc[i][j] = MFMA_BF16(af[i], bd[j], acc[i][j], 0, 0, 0);
        }
        __syncthreads();
    }

#pragma unroll
    for (int i = 0; i < 4; i++)
#pragma unroll
        for (int j = 0; j < 4; j++)
#pragma unroll
            for (int r = 0; r < 4; r++) {
                int m = wm + i * 16 + qd * 4 + r;
                if (base + m < cnt)
                    yexp[(size_t)(arow0 + m) * HD + hb0 + wn + j * 16 + l16] =
                        f2bf(acc[i][j][r]);
            }
}

// ---------------- kernel 5: weighted combine (atomic-free) ----------------
// 2 tokens per block; thread covers 8 cols. Fully overwrites out.
__global__ __launch_bounds__(256) void combine_k(
        const short* __restrict__ yexp,
        const int* __restrict__ offs,
        const int* __restrict__ tk_idx, const float* __restrict__ tk_w,
        const int* __restrict__ pair_slot,
        float* __restrict__ out) {
    int t = blockIdx.x * 2 + (threadIdx.x >> 7);
    int i = threadIdx.x & 127;          // col group of 8
    float acc[8] = {};
#pragma unroll
    for (int k = 0; k < TOPK; k++) {
        int p = t * TOPK + k;
        int e = tk_idx[p];
        int row = offs[e] + pair_slot[p];
        float w = tk_w[p];
        bf16x8 v = *(const bf16x8*)(yexp + (size_t)row * HD + i * 8);
#pragma unroll
        for (int j = 0; j < 8; j++) acc[j] += w * bf2f(v[j]);
    }
    float4 o0 = {acc[0], acc[1], acc[2], acc[3]};
    float4 o1 = {acc[4], acc[5], acc[6], acc[7]};
    float* d = out + (size_t)t * HD + i * 8;
    *(float4*)d = o0;
    *(float4*)(d + 4) = o1;
}

// ---------------- launch ----------------
extern "C" void kernel_launch(void* const* d_in, const int* in_sizes, int n_in,
                              void* d_out, int out_size, void* d_ws, size_t ws_size,
                              hipStream_t stream) {
    const float* x  = (const float*)d_in[0];   // hidden_states [T,H]
    const float* gw = (const float*)d_in[1];   // gate_weight  [E,H]
    const float* eb = (const float*)d_in[2];   // e_bias       [E]
    const float* gp = (const float*)d_in[3];   // gate_proj [E,I,H]
    const float* up = (const float*)d_in[4];   // up_proj   [E,I,H]
    const float* dp = (const float*)d_in[5];   // down_proj [E,H,I]

    short* gpb = (short*)d_ws;                  // bf16 weights: 3 x 16.8 MB
    short* upb = gpb + WELEM;
    short* dpb = upb + WELEM;
    short* xb  = dpb + WELEM;                   // x bf16: 2048x1024
    short* act = xb + (size_t)T_TOK * HD;       // (8192+128) x 512 bf16
    int* counts    = (int*)(act + (size_t)(T_TOK * TOPK + 128) * ID);
    int* offs      = counts + NE;
    int* tok_list  = offs + NE;                       // E*T
    int* pair_slot = tok_list + NE * T_TOK;           // T*4
    int* tk_idx    = pair_slot + T_TOK * TOPK;        // T*4
    float* tk_w    = (float*)(tk_idx + T_TOK * TOPK); // T*4
    // yexp bf16 (8192 x 1024 = 16.8 MB) aliases gpb (dead after gemm1;
    // exact size match). Same-stream ordering makes this safe.
    short* yexp = gpb;

    hipMemsetAsync(counts, 0, NE * sizeof(int), stream);

    conv_k<<<dim3(WELEM / 8 / 256, 3), 256, 0, stream>>>(gp, gpb, up, upb,
                                                         dp, dpb);
    router_k<<<T_TOK / 4, 256, 0, stream>>>(x, gw, eb, tk_idx, tk_w, xb);
    assign_k<<<T_TOK * TOPK / 256, 256, 0, stream>>>(tk_idx, counts,
                                                     tok_list, pair_slot);
    offs_k<<<1, 64, 0, stream>>>(counts, offs);
    gemm1_k<<<dim3(ID / 64, T_TOK / 128, NE), 256, 0, stream>>>(
        xb, gpb, upb, counts, offs, tok_list, act);
    gemm2_k<<<dim3(HD / 128, T_TOK / 128, NE), 256, 0, stream>>>(
        act, dpb, counts, offs, yexp);
    combine_k<<<T_TOK / 2, 256, 0, stream>>>(yexp, offs, tk_idx, tk_w,
                                             pair_slot, (float*)d_out);
}